// Round 8
// baseline (20274.681 us; speedup 1.0000x reference)
//
#include <hip/hip_runtime.h>
#include <math.h>

typedef float4 f4;
#define NW 248
#define NB 64
#define NT 255   // window w runs ticks w..w+7

__device__ __forceinline__ float sigm(float x)   { return __builtin_amdgcn_rcpf(1.0f + __expf(-x)); }
__device__ __forceinline__ float tanh_f(float x) { return 2.0f * __builtin_amdgcn_rcpf(1.0f + __expf(-2.0f * x)) - 1.0f; }

#define DOT4(q,W,H) { q = fmaf((W).x,(H).x,q); q = fmaf((W).y,(H).y,q); \
                      q = fmaf((W).z,(H).z,q); q = fmaf((W).w,(H).w,q); }

__global__ __launch_bounds__(512)
void or_lstm_amort(const float* __restrict__ traj,
                   const float* __restrict__ Wih0, const float* __restrict__ Whh0,
                   const float* __restrict__ bih0, const float* __restrict__ bhh0,
                   const float* __restrict__ Wih1, const float* __restrict__ Whh1,
                   const float* __restrict__ bih1, const float* __restrict__ bhh1,
                   const float* __restrict__ Wlin, const float* __restrict__ blin,
                   float* __restrict__ out)
{
    const int row  = blockIdx.x;
    const int tid  = threadIdx.x;       // ((j*4)+g)*2 + half
    const int half = tid & 1;
    const int rr   = tid >> 1;
    const int j    = rr >> 2;
    const int g    = rr & 3;            // 0=i,1=f,2=g(tanh),3=o
    const int r    = g * 64 + j;
    const int hof  = half * 32;         // float offset of K-half

    __shared__ __align__(16) float trajS[256 * 4];
    __shared__ __align__(16) float H0[2][8][64];   // [phase][slot][j]
    __shared__ __align__(16) float H1[2][8][64];
    __shared__ float ring[8][2];

    if (tid < 256)
        ((f4*)trajS)[tid] = ((const f4*)(traj + (size_t)row * 1024))[tid];
    {   // zero-init all h state (2*8*64 floats per layer)
        float* z0 = (float*)H0; float* z1 = (float*)H1;
        z0[tid] = 0.f; z0[tid + 512] = 0.f;
        z1[tid] = 0.f; z1[tid + 512] = 0.f;
    }

    // per-thread weight half-row base pointers (stream from L2 every tick;
    // each 16B chunk is FMA'd against all 8 slots -> 8x amortization)
    const f4* pA = (const f4*)(Whh0 + r * 64 + hof);
    const f4* pB = (const f4*)(Wih1 + r * 64 + hof);
    const f4* pC = (const f4*)(Whh1 + r * 64 + hof);
    const float wiA = Wih0[r * 4 + 2 * half];
    const float wiB = Wih0[r * 4 + 2 * half + 1];
    const float bb0 = half ? 0.f : (bih0[r] + bhh0[r]);
    const float bb1 = half ? 0.f : (bih1[r] + bhh1[r]);
    float wl0 = 0.f, wl1 = 0.f;
    if (tid < 64) { wl0 = Wlin[tid]; wl1 = Wlin[64 + tid]; }
    const float bl0 = blin[0], bl1 = blin[1];

    const int lane = tid & 63;
    const int gsel = (lane & ~7) + half;

    float cc0[8], cc1[8];
#pragma unroll
    for (int k = 0; k < 8; ++k) { cc0[k] = 0.f; cc1[k] = 0.f; }

    __syncthreads();

    for (int t = 0; t < NT; ++t) {
        const int ps = t & 1, pn = ps ^ 1;
        const int jo = (t - 8) & 7;

        // ---------- per-slot input features + layer-0 accumulator init ----------
        float qa[8];
#pragma unroll
        for (int k = 0; k < 8; ++k) {
            float q = 0.f;
            if (t >= k && t <= 247 + k) {              // wave-uniform
                const int s = (t - k) & 7;
                const int w = k + ((t - k) & ~7);
                float x0, x1, x2, x3;
                if (w == 0) {
                    x0 = trajS[s*4+0]; x1 = trajS[s*4+1]; x2 = trajS[s*4+2]; x3 = trajS[s*4+3];
                } else if (w < 8) {
                    if (s < 8 - w) {
                        const int tt = w + s;
                        x0 = trajS[tt*4+0]; x1 = trajS[tt*4+1]; x2 = trajS[tt*4+2]; x3 = trajS[tt*4+3];
                    } else {
                        const int tc = 2*w + s - 1;
                        x0 = trajS[tc*4+0]; x1 = trajS[tc*4+1];
                        x2 = ring[jo][0];   x3 = ring[jo][1];
                    }
                } else {
                    x0 = trajS[t*4+0]; x1 = trajS[t*4+1];
                    x2 = ring[jo][0];  x3 = ring[jo][1];
                }
                const float xa = half ? x2 : x0;
                const float xb = half ? x3 : x1;
                q = fmaf(wiA, xa, fmaf(wiB, xb, bb0));
            }
            qa[k] = q;
        }

        // ---------- layer 0 dot: Whh0 chunk-outer, slots-inner ----------
        {
            const float* hb = &H0[ps][0][hof];
            f4 w = pA[0];
            for (int c = 0; c < 8; ++c) {
                const f4 wn = pA[(c + 1) & 7];         // prefetch next chunk
                const float* hc = hb + (c << 2);
#pragma unroll
                for (int k = 0; k < 8; ++k) {
                    const f4 h = *(const f4*)(hc + (k << 6));
                    DOT4(qa[k], w, h)
                }
                w = wn;
            }
        }

        // ---------- layer 0 finalize ----------
#pragma unroll
        for (int k = 0; k < 8; ++k) {
            if (t >= k && t <= 247 + k) {
                float acc = qa[k];
                acc += __shfl_xor(acc, 1, 64);
                const float a  = (g == 2) ? tanh_f(acc) : sigm(acc);
                const float ai = __shfl(a, gsel + 0, 64);
                const float af = __shfl(a, gsel + 2, 64);
                const float ag = __shfl(a, gsel + 4, 64);
                const float ao = __shfl(a, gsel + 6, 64);
                cc0[k] = af * cc0[k] + ai * ag;        // cc0[k]==0 at s==0 (phase-C reset)
                const float h0v = ao * tanh_f(cc0[k]);
                if (g == 0 && half == 0) H0[pn][k][j] = h0v;
            }
        }
        __syncthreads();   // barrier 1: H0[pn] complete

        // ---------- layer 1 dot: Wih1 @ H0[pn] then Whh1 @ H1[ps] ----------
        float qb[8];
#pragma unroll
        for (int k = 0; k < 8; ++k) qb[k] = bb1;
        {
            const float* hb = &H0[pn][0][hof];
            f4 w = pB[0];
            for (int c = 0; c < 8; ++c) {
                const f4 wn = pB[(c + 1) & 7];
                const float* hc = hb + (c << 2);
#pragma unroll
                for (int k = 0; k < 8; ++k) {
                    const f4 h = *(const f4*)(hc + (k << 6));
                    DOT4(qb[k], w, h)
                }
                w = wn;
            }
        }
        {
            const float* hb = &H1[ps][0][hof];
            f4 w = pC[0];
            for (int c = 0; c < 8; ++c) {
                const f4 wn = pC[(c + 1) & 7];
                const float* hc = hb + (c << 2);
#pragma unroll
                for (int k = 0; k < 8; ++k) {
                    const f4 h = *(const f4*)(hc + (k << 6));
                    DOT4(qb[k], w, h)
                }
                w = wn;
            }
        }

        // ---------- layer 1 finalize ----------
#pragma unroll
        for (int k = 0; k < 8; ++k) {
            if (t >= k && t <= 247 + k) {
                float acc = qb[k];
                acc += __shfl_xor(acc, 1, 64);
                const float a  = (g == 2) ? tanh_f(acc) : sigm(acc);
                const float ai = __shfl(a, gsel + 0, 64);
                const float af = __shfl(a, gsel + 2, 64);
                const float ag = __shfl(a, gsel + 4, 64);
                const float ao = __shfl(a, gsel + 6, 64);
                cc1[k] = af * cc1[k] + ai * ag;
                const float h1v = ao * tanh_f(cc1[k]);
                if (g == 0 && half == 0) H1[pn][k][j] = h1v;
            }
        }
        __syncthreads();   // barrier 2: H1[pn] complete

        // ---------- phase C: epilogue of finishing window + slot recycle ----------
        const int kf = (t + 1) & 7;                    // slot that had s==7 this tick
        if (t >= 7 && tid < 64) {
            const int wf = t - 7;
            const float hv = H1[pn][kf][tid];
            float p0 = wl0 * hv, p1 = wl1 * hv;
#pragma unroll
            for (int off = 32; off > 0; off >>= 1) {
                p0 += __shfl_down(p0, off);
                p1 += __shfl_down(p1, off);
            }
            if (tid == 0) {
                float prev0, prev1;
                if (wf == 0) { prev0 = trajS[7*4+2];      prev1 = trajS[7*4+3]; }
                else         { prev0 = ring[(wf-1)&7][0]; prev1 = ring[(wf-1)&7][1]; }
                const float o0 = prev0 + p0 + bl0;
                const float o1 = prev1 + p1 + bl1;
                ring[wf & 7][0] = o0; ring[wf & 7][1] = o1;
                out[((size_t)row * NW + wf) * 2 + 0] = o0;
                out[((size_t)row * NW + wf) * 2 + 1] = o1;
            }
        }
        if (t == NT - 1) {                             // final h/c of window 247 (slot 7)
            if (g == 0 && half == 0) {
                float* hn = out + (size_t)NB * NW * 2;
                float* cn = hn + 2 * NB * 64;
                hn[(0 * NB + row) * 64 + j] = H0[pn][7][j];
                hn[(1 * NB + row) * 64 + j] = H1[pn][7][j];
                cn[(0 * NB + row) * 64 + j] = cc0[7];
                cn[(1 * NB + row) * 64 + j] = cc1[7];
            }
        } else {
            // recycle slot kf for the window starting at tick t+1: zero h and c
            if (tid < 64) { H0[pn][kf][tid] = 0.f; H1[pn][kf][tid] = 0.f; }
            cc0[kf] = 0.f; cc1[kf] = 0.f;
        }
        __syncthreads();   // barrier 3: ring + recycled state visible
    }
}

extern "C" void kernel_launch(void* const* d_in, const int* in_sizes, int n_in,
                              void* d_out, int out_size, void* d_ws, size_t ws_size,
                              hipStream_t stream) {
    const float* traj = (const float*)d_in[0];
    const float* Wih0 = (const float*)d_in[1];
    const float* Whh0 = (const float*)d_in[2];
    const float* bih0 = (const float*)d_in[3];
    const float* bhh0 = (const float*)d_in[4];
    const float* Wih1 = (const float*)d_in[5];
    const float* Whh1 = (const float*)d_in[6];
    const float* bih1 = (const float*)d_in[7];
    const float* bhh1 = (const float*)d_in[8];
    const float* Wlin = (const float*)d_in[9];
    const float* blin = (const float*)d_in[10];
    float* out = (float*)d_out;

    or_lstm_amort<<<dim3(NB), dim3(512), 0, stream>>>(
        traj, Wih0, Whh0, bih0, bhh0, Wih1, Whh1, bih1, bhh1, Wlin, blin, out);
}

// Round 9
// 20227.235 us; speedup vs baseline: 1.0023x; 1.0023x over previous
//
#include <hip/hip_runtime.h>
#include <math.h>

typedef float4 f4;
#define NW 248
#define NB 64
#define NT 255   // window w runs ticks w..w+7

__device__ __forceinline__ float sigm(float x)   { return __builtin_amdgcn_rcpf(1.0f + __expf(-x)); }
__device__ __forceinline__ float tanh_f(float x) { return 2.0f * __builtin_amdgcn_rcpf(1.0f + __expf(-2.0f * x)) - 1.0f; }

#define DOT4(q,W,H) { q = fmaf((W).x,(H).x,q); q = fmaf((W).y,(H).y,q); \
                      q = fmaf((W).z,(H).z,q); q = fmaf((W).w,(H).w,q); }

__global__ __launch_bounds__(512)
void or_lstm_amort(const float* __restrict__ traj,
                   const float* __restrict__ Wih0, const float* __restrict__ Whh0,
                   const float* __restrict__ bih0, const float* __restrict__ bhh0,
                   const float* __restrict__ Wih1, const float* __restrict__ Whh1,
                   const float* __restrict__ bih1, const float* __restrict__ bhh1,
                   const float* __restrict__ Wlin, const float* __restrict__ blin,
                   float* __restrict__ out)
{
    const int row  = blockIdx.x;
    const int tid  = threadIdx.x;       // ((j*4)+g)*2 + half
    const int half = tid & 1;
    const int rr   = tid >> 1;
    const int j    = rr >> 2;
    const int g    = rr & 3;            // 0=i,1=f,2=g(tanh),3=o
    const int r    = g * 64 + j;
    const int hof  = half * 32;         // float offset of K-half

    __shared__ __align__(16) float trajS[256 * 4];
    __shared__ __align__(16) float H0[2][8][64];   // [phase][slot][j]
    __shared__ __align__(16) float H1[2][8][64];
    __shared__ float ring[8][2];

    if (tid < 256)
        ((f4*)trajS)[tid] = ((const f4*)(traj + (size_t)row * 1024))[tid];
    {   // zero-init all h state
        float* z0 = (float*)H0; float* z1 = (float*)H1;
        z0[tid] = 0.f; z0[tid + 512] = 0.f;
        z1[tid] = 0.f; z1[tid + 512] = 0.f;
    }

    // per-thread weight half-row base pointers; each 16B chunk is loaded ONCE
    // per tick and FMA'd against all 8 slots (8x amortization of L2 traffic)
    const f4* pA = (const f4*)(Whh0 + r * 64 + hof);
    const f4* pB = (const f4*)(Wih1 + r * 64 + hof);
    const f4* pC = (const f4*)(Whh1 + r * 64 + hof);
    const float wiA = Wih0[r * 4 + 2 * half];
    const float wiB = Wih0[r * 4 + 2 * half + 1];
    const float bb0 = half ? 0.f : (bih0[r] + bhh0[r]);
    const float bb1 = half ? 0.f : (bih1[r] + bhh1[r]);
    float wl0 = 0.f, wl1 = 0.f;
    if (tid < 64) { wl0 = Wlin[tid]; wl1 = Wlin[64 + tid]; }
    const float bl0 = blin[0], bl1 = blin[1];

    const int lane = tid & 63;
    const int gsel = (lane & ~7) + half;

    float cc0[8], cc1[8];
#pragma unroll
    for (int k = 0; k < 8; ++k) { cc0[k] = 0.f; cc1[k] = 0.f; }

    __syncthreads();

    for (int t = 0; t < NT; ++t) {
        const int ps = t & 1, pn = ps ^ 1;
        const int jo = (t - 8) & 7;

        // ---------- per-slot input features + layer-0 accumulator init ----------
        float qa[8];
#pragma unroll
        for (int k = 0; k < 8; ++k) {
            float q = 0.f;
            if (t >= k && t <= 247 + k) {              // wave-uniform
                const int s = (t - k) & 7;
                const int w = k + ((t - k) & ~7);
                float x0, x1, x2, x3;
                if (w == 0) {
                    x0 = trajS[s*4+0]; x1 = trajS[s*4+1]; x2 = trajS[s*4+2]; x3 = trajS[s*4+3];
                } else if (w < 8) {
                    if (s < 8 - w) {
                        const int tt = w + s;
                        x0 = trajS[tt*4+0]; x1 = trajS[tt*4+1]; x2 = trajS[tt*4+2]; x3 = trajS[tt*4+3];
                    } else {
                        const int tc = 2*w + s - 1;
                        x0 = trajS[tc*4+0]; x1 = trajS[tc*4+1];
                        x2 = ring[jo][0];   x3 = ring[jo][1];
                    }
                } else {
                    x0 = trajS[t*4+0]; x1 = trajS[t*4+1];
                    x2 = ring[jo][0];  x3 = ring[jo][1];
                }
                const float xa = half ? x2 : x0;
                const float xb = half ? x3 : x1;
                q = fmaf(wiA, xa, fmaf(wiB, xb, bb0));
            }
            qa[k] = q;
        }

        // ---------- layer 0 dot: Whh0 chunk-outer (FULLY UNROLLED), slots-inner ----------
        {
            const float* hb = &H0[ps][0][hof];
            f4 w = pA[0];
#pragma unroll
            for (int c = 0; c < 8; ++c) {
                const f4 wn = pA[(c + 1) & 7];         // rotated prefetch, static index
                const float* hc = hb + (c << 2);
#pragma unroll
                for (int k = 0; k < 8; ++k) {
                    const f4 h = *(const f4*)(hc + (k << 6));
                    DOT4(qa[k], w, h)
                }
                w = wn;
            }
        }

        // ---------- layer 0 finalize ----------
#pragma unroll
        for (int k = 0; k < 8; ++k) {
            if (t >= k && t <= 247 + k) {
                float acc = qa[k];
                acc += __shfl_xor(acc, 1, 64);
                const float a  = (g == 2) ? tanh_f(acc) : sigm(acc);
                const float ai = __shfl(a, gsel + 0, 64);
                const float af = __shfl(a, gsel + 2, 64);
                const float ag = __shfl(a, gsel + 4, 64);
                const float ao = __shfl(a, gsel + 6, 64);
                cc0[k] = af * cc0[k] + ai * ag;        // cc0[k]==0 at s==0 (phase-C reset)
                const float h0v = ao * tanh_f(cc0[k]);
                if (g == 0 && half == 0) H0[pn][k][j] = h0v;
            }
        }
        __syncthreads();   // barrier 1: H0[pn] complete

        // ---------- layer 1 dot: Wih1 @ H0[pn] then Whh1 @ H1[ps] ----------
        float qb[8];
#pragma unroll
        for (int k = 0; k < 8; ++k) qb[k] = bb1;
        {
            const float* hb = &H0[pn][0][hof];
            f4 w = pB[0];
#pragma unroll
            for (int c = 0; c < 8; ++c) {
                const f4 wn = pB[(c + 1) & 7];
                const float* hc = hb + (c << 2);
#pragma unroll
                for (int k = 0; k < 8; ++k) {
                    const f4 h = *(const f4*)(hc + (k << 6));
                    DOT4(qb[k], w, h)
                }
                w = wn;
            }
        }
        {
            const float* hb = &H1[ps][0][hof];
            f4 w = pC[0];
#pragma unroll
            for (int c = 0; c < 8; ++c) {
                const f4 wn = pC[(c + 1) & 7];
                const float* hc = hb + (c << 2);
#pragma unroll
                for (int k = 0; k < 8; ++k) {
                    const f4 h = *(const f4*)(hc + (k << 6));
                    DOT4(qb[k], w, h)
                }
                w = wn;
            }
        }

        // ---------- layer 1 finalize ----------
#pragma unroll
        for (int k = 0; k < 8; ++k) {
            if (t >= k && t <= 247 + k) {
                float acc = qb[k];
                acc += __shfl_xor(acc, 1, 64);
                const float a  = (g == 2) ? tanh_f(acc) : sigm(acc);
                const float ai = __shfl(a, gsel + 0, 64);
                const float af = __shfl(a, gsel + 2, 64);
                const float ag = __shfl(a, gsel + 4, 64);
                const float ao = __shfl(a, gsel + 6, 64);
                cc1[k] = af * cc1[k] + ai * ag;
                const float h1v = ao * tanh_f(cc1[k]);
                if (g == 0 && half == 0) H1[pn][k][j] = h1v;
            }
        }
        __syncthreads();   // barrier 2: H1[pn] complete

        // ---------- phase C: epilogue of finishing window + slot recycle ----------
        const int kf = (t + 1) & 7;                    // slot that had s==7 this tick
        if (t >= 7 && tid < 64) {
            const int wf = t - 7;
            const float hv = H1[pn][kf][tid];
            float p0 = wl0 * hv, p1 = wl1 * hv;
#pragma unroll
            for (int off = 32; off > 0; off >>= 1) {
                p0 += __shfl_down(p0, off);
                p1 += __shfl_down(p1, off);
            }
            if (tid == 0) {
                float prev0, prev1;
                if (wf == 0) { prev0 = trajS[7*4+2];      prev1 = trajS[7*4+3]; }
                else         { prev0 = ring[(wf-1)&7][0]; prev1 = ring[(wf-1)&7][1]; }
                const float o0 = prev0 + p0 + bl0;
                const float o1 = prev1 + p1 + bl1;
                ring[wf & 7][0] = o0; ring[wf & 7][1] = o1;
                out[((size_t)row * NW + wf) * 2 + 0] = o0;
                out[((size_t)row * NW + wf) * 2 + 1] = o1;
            }
        }
        if (t == NT - 1) {                             // final h/c of window 247 (slot 7)
            if (g == 0 && half == 0) {
                float* hn = out + (size_t)NB * NW * 2;
                float* cn = hn + 2 * NB * 64;
                hn[(0 * NB + row) * 64 + j] = H0[pn][7][j];
                hn[(1 * NB + row) * 64 + j] = H1[pn][7][j];
                cn[(0 * NB + row) * 64 + j] = cc0[7];
                cn[(1 * NB + row) * 64 + j] = cc1[7];
            }
        } else {
            // recycle slot kf for the window starting at tick t+1: zero h and c
            if (tid < 64) { H0[pn][kf][tid] = 0.f; H1[pn][kf][tid] = 0.f; }
            cc0[kf] = 0.f; cc1[kf] = 0.f;
        }
        __syncthreads();   // barrier 3: ring + recycled state visible
    }
}

extern "C" void kernel_launch(void* const* d_in, const int* in_sizes, int n_in,
                              void* d_out, int out_size, void* d_ws, size_t ws_size,
                              hipStream_t stream) {
    const float* traj = (const float*)d_in[0];
    const float* Wih0 = (const float*)d_in[1];
    const float* Whh0 = (const float*)d_in[2];
    const float* bih0 = (const float*)d_in[3];
    const float* bhh0 = (const float*)d_in[4];
    const float* Wih1 = (const float*)d_in[5];
    const float* Whh1 = (const float*)d_in[6];
    const float* bih1 = (const float*)d_in[7];
    const float* bhh1 = (const float*)d_in[8];
    const float* Wlin = (const float*)d_in[9];
    const float* blin = (const float*)d_in[10];
    float* out = (float*)d_out;

    or_lstm_amort<<<dim3(NB), dim3(512), 0, stream>>>(
        traj, Wih0, Whh0, bih0, bhh0, Wih1, Whh1, bih1, bhh1, Wlin, blin, out);
}

// Round 10
// 17148.984 us; speedup vs baseline: 1.1823x; 1.1795x over previous
//
#include <hip/hip_runtime.h>
#include <math.h>

typedef float4 f4;
#define NW 248
#define NB 64
#define NT 255   // window w runs ticks w..w+7

__device__ __forceinline__ float sigm(float x)   { return __builtin_amdgcn_rcpf(1.0f + __expf(-x)); }
__device__ __forceinline__ float tanh_f(float x) { return 2.0f * __builtin_amdgcn_rcpf(1.0f + __expf(-2.0f * x)) - 1.0f; }

#define DOT4(q,W,H) { q = fmaf((W).x,(H).x,q); q = fmaf((W).y,(H).y,q); \
                      q = fmaf((W).z,(H).z,q); q = fmaf((W).w,(H).w,q); }

// one weight chunk (16B) FMA'd against all 8 slots' h-chunks (LDS broadcast)
#define CH(c, Q, HB, P) { const f4 wch = (P)[c]; const float* hc = (HB) + ((c) << 2); \
  { const f4 h = *(const f4*)(hc +   0); DOT4(Q##0, wch, h) } \
  { const f4 h = *(const f4*)(hc +  64); DOT4(Q##1, wch, h) } \
  { const f4 h = *(const f4*)(hc + 128); DOT4(Q##2, wch, h) } \
  { const f4 h = *(const f4*)(hc + 192); DOT4(Q##3, wch, h) } \
  { const f4 h = *(const f4*)(hc + 256); DOT4(Q##4, wch, h) } \
  { const f4 h = *(const f4*)(hc + 320); DOT4(Q##5, wch, h) } \
  { const f4 h = *(const f4*)(hc + 384); DOT4(Q##6, wch, h) } \
  { const f4 h = *(const f4*)(hc + 448); DOT4(Q##7, wch, h) } }

#define MAT8(Q, HB, P) CH(0,Q,HB,P) CH(1,Q,HB,P) CH(2,Q,HB,P) CH(3,Q,HB,P) \
                       CH(4,Q,HB,P) CH(5,Q,HB,P) CH(6,Q,HB,P) CH(7,Q,HB,P)

// per-slot input features + layer-0 accumulator init (scalar target qa##k)
#define QINIT(k) { float q = 0.f; \
  if (t >= k && t <= 247 + k) { \
    const int s = (t - k) & 7; \
    const int w = k + ((t - k) & ~7); \
    float x0, x1, x2, x3; \
    if (w == 0) { x0=trajS[s*4+0]; x1=trajS[s*4+1]; x2=trajS[s*4+2]; x3=trajS[s*4+3]; } \
    else if (w < 8) { \
      if (s < 8 - w) { const int tt = w + s; \
        x0=trajS[tt*4+0]; x1=trajS[tt*4+1]; x2=trajS[tt*4+2]; x3=trajS[tt*4+3]; } \
      else { const int tc = 2*w + s - 1; \
        x0=trajS[tc*4+0]; x1=trajS[tc*4+1]; x2=ring[jo][0]; x3=ring[jo][1]; } \
    } else { x0=trajS[t*4+0]; x1=trajS[t*4+1]; x2=ring[jo][0]; x3=ring[jo][1]; } \
    const float xa = half ? x2 : x0; \
    const float xb = half ? x3 : x1; \
    q = fmaf(wiA, xa, fmaf(wiB, xb, bb0)); } \
  qa##k = q; }

#define QINIT8 QINIT(0) QINIT(1) QINIT(2) QINIT(3) QINIT(4) QINIT(5) QINIT(6) QINIT(7)

// gate activation + in-wave gather + cell update for slot k (all names static)
#define FIN(k, Q, C, Hd) if (t >= k && t <= 247 + k) { \
  float acc = Q##k; acc += __shfl_xor(acc, 1, 64); \
  const float a  = (g == 2) ? tanh_f(acc) : sigm(acc); \
  const float ai = __shfl(a, gsel + 0, 64); \
  const float af = __shfl(a, gsel + 2, 64); \
  const float ag = __shfl(a, gsel + 4, 64); \
  const float ao = __shfl(a, gsel + 6, 64); \
  C##k = af * C##k + ai * ag; \
  const float hv = ao * tanh_f(C##k); \
  if (g == 0 && half == 0) Hd[k][j] = hv; }

#define FIN8(Q, C, Hd) FIN(0,Q,C,Hd) FIN(1,Q,C,Hd) FIN(2,Q,C,Hd) FIN(3,Q,C,Hd) \
                       FIN(4,Q,C,Hd) FIN(5,Q,C,Hd) FIN(6,Q,C,Hd) FIN(7,Q,C,Hd)

// slot recycle with STATIC names (the runtime-indexed cc0[kf]=0 was the
// R8/R9 scratch catastrophe: dynamic index -> SROA fails -> 16 GB spill)
#define RECYC(k) { if (kf == k) { c0##k = 0.f; c1##k = 0.f; } }
#define RECYC8 RECYC(0) RECYC(1) RECYC(2) RECYC(3) RECYC(4) RECYC(5) RECYC(6) RECYC(7)

__global__ __launch_bounds__(512)
void or_lstm_scal(const float* __restrict__ traj,
                  const float* __restrict__ Wih0, const float* __restrict__ Whh0,
                  const float* __restrict__ bih0, const float* __restrict__ bhh0,
                  const float* __restrict__ Wih1, const float* __restrict__ Whh1,
                  const float* __restrict__ bih1, const float* __restrict__ bhh1,
                  const float* __restrict__ Wlin, const float* __restrict__ blin,
                  float* __restrict__ out)
{
    const int row  = blockIdx.x;
    const int tid  = threadIdx.x;       // ((j*4)+g)*2 + half
    const int half = tid & 1;
    const int rr   = tid >> 1;
    const int j    = rr >> 2;
    const int g    = rr & 3;            // 0=i,1=f,2=g(tanh),3=o
    const int r    = g * 64 + j;
    const int hof  = half * 32;

    __shared__ __align__(16) float trajS[256 * 4];
    __shared__ __align__(16) float H0[2][8][64];
    __shared__ __align__(16) float H1[2][8][64];
    __shared__ float ring[8][2];

    if (tid < 256)
        ((f4*)trajS)[tid] = ((const f4*)(traj + (size_t)row * 1024))[tid];
    {
        float* z0 = (float*)H0; float* z1 = (float*)H1;
        z0[tid] = 0.f; z0[tid + 512] = 0.f;
        z1[tid] = 0.f; z1[tid + 512] = 0.f;
    }

    const f4* pA = (const f4*)(Whh0 + r * 64 + hof);
    const f4* pB = (const f4*)(Wih1 + r * 64 + hof);
    const f4* pC = (const f4*)(Whh1 + r * 64 + hof);
    const float wiA = Wih0[r * 4 + 2 * half];
    const float wiB = Wih0[r * 4 + 2 * half + 1];
    const float bb0 = half ? 0.f : (bih0[r] + bhh0[r]);
    const float bb1 = half ? 0.f : (bih1[r] + bhh1[r]);
    float wl0 = 0.f, wl1 = 0.f;
    if (tid < 64) { wl0 = Wlin[tid]; wl1 = Wlin[64 + tid]; }
    const float bl0 = blin[0], bl1 = blin[1];

    const int lane = tid & 63;
    const int gsel = (lane & ~7) + half;

    // cell states: NAMED scalars only (no arrays anywhere in this kernel)
    float c00=0.f,c01=0.f,c02=0.f,c03=0.f,c04=0.f,c05=0.f,c06=0.f,c07=0.f;
    float c10=0.f,c11=0.f,c12=0.f,c13=0.f,c14=0.f,c15=0.f,c16=0.f,c17=0.f;

    __syncthreads();

    for (int t = 0; t < NT; ++t) {
        const int ps = t & 1, pn = ps ^ 1;
        const int jo = (t - 8) & 7;

        float qa0,qa1,qa2,qa3,qa4,qa5,qa6,qa7;
        QINIT8

        // ---------- layer 0: Whh0 chunk-outer, slots-inner ----------
        {
            const float* hb0 = &H0[ps][0][hof];
            MAT8(qa, hb0, pA)
        }
        {
            float (*Hd)[64] = H0[pn];
            FIN8(qa, c0, Hd)
        }
        __syncthreads();   // barrier 1: H0[pn] complete

        // ---------- layer 1: Wih1 @ H0[pn], Whh1 @ H1[ps] ----------
        float qb0=bb1,qb1=bb1,qb2=bb1,qb3=bb1,qb4=bb1,qb5=bb1,qb6=bb1,qb7=bb1;
        {
            const float* hbx = &H0[pn][0][hof];
            MAT8(qb, hbx, pB)
            const float* hbh = &H1[ps][0][hof];
            MAT8(qb, hbh, pC)
        }
        {
            float (*Hd)[64] = H1[pn];
            FIN8(qb, c1, Hd)
        }
        __syncthreads();   // barrier 2: H1[pn] complete

        // ---------- phase C: epilogue of finishing window + slot recycle ----------
        const int kf = (t + 1) & 7;
        if (t >= 7 && tid < 64) {
            const int wf = t - 7;
            const float hv = H1[pn][kf][tid];
            float p0 = wl0 * hv, p1 = wl1 * hv;
#pragma unroll
            for (int off = 32; off > 0; off >>= 1) {
                p0 += __shfl_down(p0, off);
                p1 += __shfl_down(p1, off);
            }
            if (tid == 0) {
                float prev0, prev1;
                if (wf == 0) { prev0 = trajS[7*4+2];      prev1 = trajS[7*4+3]; }
                else         { prev0 = ring[(wf-1)&7][0]; prev1 = ring[(wf-1)&7][1]; }
                const float o0 = prev0 + p0 + bl0;
                const float o1 = prev1 + p1 + bl1;
                ring[wf & 7][0] = o0; ring[wf & 7][1] = o1;
                out[((size_t)row * NW + wf) * 2 + 0] = o0;
                out[((size_t)row * NW + wf) * 2 + 1] = o1;
            }
        }
        if (t == NT - 1) {
            if (g == 0 && half == 0) {   // final h/c of window 247 (slot 7)
                float* hn = out + (size_t)NB * NW * 2;
                float* cn = hn + 2 * NB * 64;
                hn[(0 * NB + row) * 64 + j] = H0[pn][7][j];
                hn[(1 * NB + row) * 64 + j] = H1[pn][7][j];
                cn[(0 * NB + row) * 64 + j] = c07;
                cn[(1 * NB + row) * 64 + j] = c17;
            }
        } else {
            if (tid < 64) { H0[pn][kf][tid] = 0.f; H1[pn][kf][tid] = 0.f; }
            RECYC8
        }
        __syncthreads();   // barrier 3: ring + recycled state visible
    }
}

extern "C" void kernel_launch(void* const* d_in, const int* in_sizes, int n_in,
                              void* d_out, int out_size, void* d_ws, size_t ws_size,
                              hipStream_t stream) {
    const float* traj = (const float*)d_in[0];
    const float* Wih0 = (const float*)d_in[1];
    const float* Whh0 = (const float*)d_in[2];
    const float* bih0 = (const float*)d_in[3];
    const float* bhh0 = (const float*)d_in[4];
    const float* Wih1 = (const float*)d_in[5];
    const float* Whh1 = (const float*)d_in[6];
    const float* bih1 = (const float*)d_in[7];
    const float* bhh1 = (const float*)d_in[8];
    const float* Wlin = (const float*)d_in[9];
    const float* blin = (const float*)d_in[10];
    float* out = (float*)d_out;

    or_lstm_scal<<<dim3(NB), dim3(512), 0, stream>>>(
        traj, Wih0, Whh0, bih0, bhh0, Wih1, Whh1, bih1, bhh1, Wlin, blin, out);
}